// Round 9
// baseline (469.939 us; speedup 1.0000x reference)
//
#include <hip/hip_runtime.h>
#include <math.h>

#define DIM 512
#define NE 4096
#define NROWS 65536
#define MARGIN 0.6f            // ~12 sigma of single-bf16 scan noise

typedef __attribute__((ext_vector_type(8))) short short8;
typedef __attribute__((ext_vector_type(4))) float f32x4;

// ---- bf16 helpers (round-to-nearest-even) ----
__device__ inline unsigned short f2bf(float f) {
    union { float f; unsigned int u; } v; v.f = f;
    unsigned int u = v.u;
    return (unsigned short)((u + 0x7fffu + ((u >> 16) & 1u)) >> 16);
}
__device__ inline float bf2f(unsigned short h) {
    union { unsigned int u; float f; } v; v.u = ((unsigned int)h) << 16;
    return v.f;
}
__device__ inline short hi_bf(float f) { return (short)f2bf(f); }

__device__ inline bool lexlt(float v1, int i1, float v2, int i2) {
    return (v1 < v2) || (v1 == v2 && i1 < i2);
}

// fragment-ordered short index for hi image, 32-code panels:
//   panel p=e>>5, section sec=(d>>5)*2+((e>>4)&1) (0..31),
//   granule g=((d>>3)&3)*16+(e&15) (0..63), elem d&7
//   idx = p*16384 + (sec*64+g)*8 + (d&7)        [bijective: 5+6+3 = 14 bits]
__device__ __forceinline__ size_t ehf_idx(int e, int d) {
    return (size_t)(e >> 5) * 16384 +
           (size_t)(((((d >> 5) * 2 + ((e >> 4) & 1)) * 64) + ((d >> 3) & 3) * 16 + (e & 15)) * 8 + (d & 7));
}

// ---- async global->LDS (16B/lane; LDS dest = wave-uniform base + lane*16) ----
typedef __attribute__((address_space(1))) const void gconst_t;
typedef __attribute__((address_space(3))) void ldsv_t;
__device__ __forceinline__ void gload_lds16(const void* g, void* l) {
    __builtin_amdgcn_global_load_lds((gconst_t*)g, (ldsv_t*)l, 16, 0, 0);
}

// ---------------- codebook column norms (fp32, proven R1) ----------------
__global__ void norms_kernel(const float* __restrict__ embed, float* __restrict__ norms) {
    int e = blockIdx.x * blockDim.x + threadIdx.x;
    if (e < NE) {
        float s = 0.f;
        #pragma unroll 8
        for (int d = 0; d < DIM; ++d) {
            float v = embed[(size_t)d * NE + e];
            s += v * v;
        }
        norms[e] = s;
    }
}

// ---------------- transpose + hi/lo split ----------------
__global__ void prep_kernel(const float* __restrict__ embed,
                            unsigned short* __restrict__ ehf,
                            unsigned short* __restrict__ el) {
    __shared__ float t[64][65];
    const int tid = threadIdx.x;                 // 256
    const int e0 = blockIdx.x * 64;              // 64 blocks
    const int d0 = blockIdx.y * 64;              // 8 blocks
    for (int i = tid; i < 4096; i += 256) {
        int r = i >> 6, c = i & 63;              // r: d, c: e  (coalesced in e)
        t[r][c] = embed[(size_t)(d0 + r) * NE + e0 + c];
    }
    __syncthreads();
    for (int i = tid; i < 4096; i += 256) {
        int r = i >> 6, c = i & 63;              // r: e, c: d
        float v = t[c][r];
        int e = e0 + r, d = d0 + c;
        unsigned short h = f2bf(v);
        ehf[ehf_idx(e, d)] = h;
        el[(size_t)e * 512 + d] = f2bf(v - bf2f(h));
    }
}

// ---------------- main: 1-pass bf16 MFMA scan, 4-wave blocks (2 blocks/CU),
//                  DMA-staged fragment-ordered dbuf LDS, top-2 -> top-4 -> rescore ----
__global__ __launch_bounds__(256, 2) void vq_main(
        const float* __restrict__ x,
        const unsigned short* __restrict__ ehf,
        const unsigned short* __restrict__ el,
        const float* __restrict__ norms,
        float* __restrict__ out_idx,
        int* __restrict__ idx_ws) {

    __shared__ unsigned short ph[2][32 * 512];   // 2 x 32768 B, fragment order
    __shared__ int   bi4[128][4];
    __shared__ float bgap[128];

    const int tid = threadIdx.x;
    const int w   = tid >> 6;                    // wave 0..3
    const int l   = tid & 63;
    const int lr  = l & 15;
    const int lg  = l >> 4;
    const int row0 = blockIdx.x * 128;

    // ---- A fragments: 2 rowsets x 16 ks, single bf16 ----
    short8 a[2][16];
    #pragma unroll
    for (int s = 0; s < 2; ++s) {
        const float* xp = x + (size_t)(row0 + w * 32 + s * 16 + lr) * DIM + lg * 8;
        #pragma unroll
        for (int ks = 0; ks < 16; ++ks) {
            float4 u  = *(const float4*)(xp + ks * 32);
            float4 v2 = *(const float4*)(xp + ks * 32 + 4);
            short8 h;
            h[0]=hi_bf(u.x);  h[1]=hi_bf(u.y);  h[2]=hi_bf(u.z);  h[3]=hi_bf(u.w);
            h[4]=hi_bf(v2.x); h[5]=hi_bf(v2.y); h[6]=hi_bf(v2.z); h[7]=hi_bf(v2.w);
            a[s][ks] = h;
        }
    }

    float t1v[2][4], t2v[2][4]; int t1i[2][4], t2i[2][4];
    #pragma unroll
    for (int s = 0; s < 2; ++s)
        #pragma unroll
        for (int r = 0; r < 4; ++r) {
            t1v[s][r]=INFINITY; t2v[s][r]=INFINITY;
            t1i[s][r]=0x7ffffffe; t2i[s][r]=0x7fffffff;
        }

    // ---- DMA stage: 32-code panel p -> buffer b (byte-linear; per wave 8 x 1KB) ----
    #define STAGE_PANEL(p, b)                                                   \
    {                                                                           \
        const unsigned short* gsrc = ehf + (size_t)(p) * 16384 + w * 4096 + l * 8; \
        unsigned short* ldst = &ph[b][w * 4096];                                \
        _Pragma("unroll")                                                       \
        for (int j = 0; j < 8; ++j)                                             \
            gload_lds16(gsrc + j * 512, ldst + j * 512);                        \
    }

    STAGE_PANEL(0, 0)
    __syncthreads();                             // drains DMA (vmcnt0) + barrier

    #pragma unroll 1
    for (int ct = 0; ct < 128; ++ct) {
        const int cur = ct & 1;

        // issue next panel's DMA; stays in flight until end-of-loop barrier
        if (ct < 127) STAGE_PANEL(ct + 1, cur ^ 1)

        f32x4 acc[2][2];
        #pragma unroll
        for (int s = 0; s < 2; ++s)
            #pragma unroll
            for (int cb = 0; cb < 2; ++cb) acc[s][cb] = (f32x4){0.f,0.f,0.f,0.f};

        #pragma unroll
        for (int ks = 0; ks < 16; ++ks) {
            #pragma unroll
            for (int cb = 0; cb < 2; ++cb) {
                // fragment order: section (ks*2+cb), lane granule l
                short8 bh = *(const short8*)&ph[cur][(ks * 2 + cb) * 512 + l * 8];
                acc[0][cb] = __builtin_amdgcn_mfma_f32_16x16x32_bf16(a[0][ks], bh, acc[0][cb], 0, 0, 0);
                acc[1][cb] = __builtin_amdgcn_mfma_f32_16x16x32_bf16(a[1][ks], bh, acc[1][cb], 0, 0, 0);
            }
        }

        // epilogue: s = ||e||^2 - 2*dot ; per-lane top-2 (ascending e)
        #pragma unroll
        for (int cb = 0; cb < 2; ++cb) {
            int e = ct * 32 + cb * 16 + lr;
            float nrm = norms[e];
            #pragma unroll
            for (int s = 0; s < 2; ++s)
                #pragma unroll
                for (int r = 0; r < 4; ++r) {
                    float sv = fmaf(-2.0f, acc[s][cb][r], nrm);
                    if (sv < t1v[s][r]) { t2v[s][r]=t1v[s][r]; t2i[s][r]=t1i[s][r]; t1v[s][r]=sv; t1i[s][r]=e; }
                    else if (sv < t2v[s][r]) { t2v[s][r]=sv; t2i[s][r]=e; }
                }
        }
        __syncthreads();   // drains panel reads (lgkm) + next-panel DMA (vmcnt)
    }
    #undef STAGE_PANEL

    // ---- per-slot: butterfly-merge per-lane top-2 lists into global top-4 ----
    #pragma unroll
    for (int s = 0; s < 2; ++s) {
        #pragma unroll
        for (int r = 0; r < 4; ++r) {
            float av[4] = { t1v[s][r], t2v[s][r], INFINITY, INFINITY };
            int   ai[4] = { t1i[s][r], t2i[s][r], 0x7ffffffe, 0x7fffffff };
            #pragma unroll
            for (int m = 1; m < 16; m <<= 1) {
                float bv[4]; int bi_[4];
                #pragma unroll
                for (int q = 0; q < 4; ++q) {
                    bv[q]  = __shfl_xor(av[q], m, 64);
                    bi_[q] = __shfl_xor(ai[q], m, 64);
                }
                float cv[4]; int ci[4];
                #pragma unroll
                for (int q = 0; q < 4; ++q) {
                    bool t = lexlt(av[q], ai[q], bv[3 - q], bi_[3 - q]);
                    cv[q] = t ? av[q] : bv[3 - q];
                    ci[q] = t ? ai[q] : bi_[3 - q];
                }
                #define CE(A,B) { if (!lexlt(cv[A],ci[A],cv[B],ci[B])) { \
                    float tv=cv[A]; cv[A]=cv[B]; cv[B]=tv; int ti=ci[A]; ci[A]=ci[B]; ci[B]=ti; } }
                CE(0,2) CE(1,3) CE(0,1) CE(2,3)
                #undef CE
                #pragma unroll
                for (int q = 0; q < 4; ++q) { av[q] = cv[q]; ai[q] = ci[q]; }
            }
            if (lr == 0) {
                int rowloc = w * 32 + s * 16 + lg * 4 + r;
                #pragma unroll
                for (int q = 0; q < 4; ++q) bi4[rowloc][q] = ai[q];
                bgap[rowloc] = av[1] - av[0];
            }
        }
    }
    __syncthreads();

    // ---- margin-gated exact rescore (x fp32, e = hi+lo) of the 4 candidates ----
    #pragma unroll 1
    for (int rr = 0; rr < 32; ++rr) {
        int rowloc = w * 32 + rr;
        int grow = row0 + rowloc;
        float gap = bgap[rowloc];
        int c0 = bi4[rowloc][0] & (NE - 1);
        if (gap > MARGIN) {
            if (l == 0) { out_idx[grow] = (float)c0; idx_ws[grow] = c0; }
            continue;
        }
        int cand[4];
        cand[0] = c0;
        cand[1] = bi4[rowloc][1] & (NE - 1);
        cand[2] = bi4[rowloc][2] & (NE - 1);
        cand[3] = bi4[rowloc][3] & (NE - 1);

        const float* xr = x + (size_t)grow * DIM + l * 8;
        float4 xa = *(const float4*)xr, xb = *(const float4*)(xr + 4);
        float xv[8] = {xa.x, xa.y, xa.z, xa.w, xb.x, xb.y, xb.z, xb.w};

        float d[4];
        #pragma unroll
        for (int q = 0; q < 4; ++q) {
            uint4 hv = *(const uint4*)&ehf[ehf_idx(cand[q], l * 8)];
            uint4 lv = *(const uint4*)&el[(size_t)cand[q] * 512 + l * 8];
            const unsigned short* hp = (const unsigned short*)&hv;
            const unsigned short* lp = (const unsigned short*)&lv;
            float acc = 0.f;
            #pragma unroll
            for (int j = 0; j < 8; ++j) acc += xv[j] * (bf2f(hp[j]) + bf2f(lp[j]));
            d[q] = acc;
        }
        #pragma unroll
        for (int m = 32; m >= 1; m >>= 1) {
            #pragma unroll
            for (int q = 0; q < 4; ++q) d[q] += __shfl_xor(d[q], m, 64);
        }
        if (l == 0) {
            float bs = norms[cand[0]] - 2.0f * d[0];
            int   bi = cand[0];
            #pragma unroll
            for (int q = 1; q < 4; ++q) {
                float sq = norms[cand[q]] - 2.0f * d[q];
                if (sq < bs || (sq == bs && cand[q] < bi)) { bs = sq; bi = cand[q]; }
            }
            out_idx[grow] = (float)bi;
            idx_ws[grow] = bi;
        }
    }
}

// ---------------- gather + diff partials (hi fragment-ordered + lo linear) ----------------
__global__ void gather_kernel(const float* __restrict__ x,
                              const unsigned short* __restrict__ ehf,
                              const unsigned short* __restrict__ el,
                              const int* __restrict__ idx, float* __restrict__ out_q,
                              float* __restrict__ partial) {
    __shared__ float red[256];
    const int tid = threadIdx.x;
    float local = 0.f;
    #pragma unroll 1
    for (int j = 0; j < 8; ++j) {
        int o8 = blockIdx.x * 2048 + j * 256 + tid;   // octet unit
        int r  = o8 >> 6;                             // 64 octets per row
        int c8 = o8 & 63;
        int e  = idx[r];
        uint4 hv = *(const uint4*)&ehf[ehf_idx(e, c8 * 8)];
        uint4 lv = *(const uint4*)&el[(size_t)e * 512 + c8 * 8];
        const unsigned short* hp = (const unsigned short*)&hv;
        const unsigned short* lp = (const unsigned short*)&lv;
        float q[8];
        #pragma unroll
        for (int k = 0; k < 8; ++k) q[k] = bf2f(hp[k]) + bf2f(lp[k]);
        float4 xa = *(const float4*)&x[(size_t)r * DIM + c8 * 8];
        float4 xb = *(const float4*)&x[(size_t)r * DIM + c8 * 8 + 4];
        *(float4*)&out_q[(size_t)r * DIM + c8 * 8]     = make_float4(q[0], q[1], q[2], q[3]);
        *(float4*)&out_q[(size_t)r * DIM + c8 * 8 + 4] = make_float4(q[4], q[5], q[6], q[7]);
        float xs[8] = {xa.x, xa.y, xa.z, xa.w, xb.x, xb.y, xb.z, xb.w};
        #pragma unroll
        for (int k = 0; k < 8; ++k) { float t = q[k] - xs[k]; local += t * t; }
    }
    red[tid] = local;
    __syncthreads();
    for (int s = 128; s > 0; s >>= 1) {
        if (tid < s) red[tid] += red[tid + s];
        __syncthreads();
    }
    if (tid == 0) partial[blockIdx.x] = red[0];
}

// ---------------- deterministic diff reduction ----------------
__global__ void diff_kernel(const float* __restrict__ partial, float* __restrict__ out_diff) {
    __shared__ float red[256];
    float s = 0.f;
    for (int i = threadIdx.x; i < 2048; i += 256) s += partial[i];
    red[threadIdx.x] = s;
    __syncthreads();
    for (int st = 128; st > 0; st >>= 1) {
        if (threadIdx.x < st) red[threadIdx.x] += red[threadIdx.x + st];
        __syncthreads();
    }
    if (threadIdx.x == 0)
        out_diff[0] = red[0] * (1.0f / ((float)NROWS * (float)DIM));
}

// ================= fallback path (R1, proven; needs only 24 KB ws) =================
#define BM 32
#define BN 64
#define BK 16
__global__ __launch_bounds__(256) void vq_kernel_fb(
        const float* __restrict__ x, const float* __restrict__ embed,
        const float* __restrict__ norms, float* __restrict__ out_q,
        float* __restrict__ out_idx, float* __restrict__ partial) {
    __shared__ float xs[BM][BK + 1];
    __shared__ float es[BK][BN];
    __shared__ float rv[BM][17];
    __shared__ int   ri[BM][17];
    __shared__ float bestv[BM];
    __shared__ int   besti[BM];
    __shared__ float red[256];
    const int tid = threadIdx.x;
    const int tc  = tid & 15;
    const int tr  = tid >> 4;
    const int row0 = blockIdx.x * BM;
    if (tid < BM) { bestv[tid] = INFINITY; besti[tid] = 0; }
    __syncthreads();
    for (int ct = 0; ct < NE / BN; ++ct) {
        float acc[2][4] = {{0.f,0.f,0.f,0.f},{0.f,0.f,0.f,0.f}};
        for (int k0 = 0; k0 < DIM; k0 += BK) {
            {
                int r = tid >> 3;
                int k = (tid & 7) * 2;
                const float* src = &x[(size_t)(row0 + r) * DIM + k0 + k];
                xs[r][k] = src[0]; xs[r][k + 1] = src[1];
            }
            {
                int r = tid >> 4;
                int c = (tid & 15) * 4;
                float4 v = *(const float4*)&embed[(size_t)(k0 + r) * NE + ct * BN + c];
                *(float4*)&es[r][c] = v;
            }
            __syncthreads();
            #pragma unroll
            for (int kk = 0; kk < BK; ++kk) {
                float a0 = xs[tr * 2 + 0][kk];
                float a1 = xs[tr * 2 + 1][kk];
                float4 b = *(const float4*)&es[kk][tc * 4];
                acc[0][0] += a0 * b.x; acc[0][1] += a0 * b.y;
                acc[0][2] += a0 * b.z; acc[0][3] += a0 * b.w;
                acc[1][0] += a1 * b.x; acc[1][1] += a1 * b.y;
                acc[1][2] += a1 * b.z; acc[1][3] += a1 * b.w;
            }
            __syncthreads();
        }
        #pragma unroll
        for (int i = 0; i < 2; ++i) {
            float bv = INFINITY; int bj = 0;
            #pragma unroll
            for (int j = 0; j < 4; ++j) {
                int e = ct * BN + tc * 4 + j;
                float s = norms[e] - 2.0f * acc[i][j];
                if (s < bv) { bv = s; bj = e; }
            }
            rv[tr * 2 + i][tc] = bv; ri[tr * 2 + i][tc] = bj;
        }
        __syncthreads();
        if (tid < BM) {
            float bv = bestv[tid]; int bi = besti[tid];
            #pragma unroll
            for (int t = 0; t < 16; ++t) {
                float v = rv[tid][t];
                if (v < bv) { bv = v; bi = ri[tid][t]; }
            }
            bestv[tid] = bv; besti[tid] = bi;
        }
        __syncthreads();
    }
    if (tid < BM) out_idx[row0 + tid] = (float)besti[tid];
    __syncthreads();
    float local = 0.f;
    for (int i = tid; i < BM * DIM; i += 256) {
        int r = i >> 9;
        int d = i & (DIM - 1);
        int e = besti[r];
        float q  = embed[(size_t)d * NE + e];
        float xv = x[(size_t)(row0 + r) * DIM + d];
        out_q[(size_t)(row0 + r) * DIM + d] = q;
        float t = q - xv;
        local += t * t;
    }
    red[tid] = local;
    __syncthreads();
    for (int s = 128; s > 0; s >>= 1) {
        if (tid < s) red[tid] += red[tid + s];
        __syncthreads();
    }
    if (tid == 0) partial[blockIdx.x] = red[0];
}

extern "C" void kernel_launch(void* const* d_in, const int* in_sizes, int n_in,
                              void* d_out, int out_size, void* d_ws, size_t ws_size,
                              hipStream_t stream) {
    (void)in_sizes; (void)n_in; (void)out_size;
    const float* x     = (const float*)d_in[0];
    const float* embed = (const float*)d_in[1];

    float* out      = (float*)d_out;
    float* out_q    = out;
    float* out_diff = out + (size_t)NROWS * DIM;
    float* out_idx  = out_diff + 1;

    const size_t NEED = 4194304ull * 2 + 16384 + 8192 + 262144;  // ehf+el+norms+partial+idx

    char* wsb = (char*)d_ws;
    if (ws_size >= NEED) {
        unsigned short* ehf     = (unsigned short*)wsb;               // 4194304 B
        unsigned short* el      = (unsigned short*)(wsb + 4194304);   // 4194304 B
        float*          norms   = (float*)(wsb + 8388608);            //   16384 B
        float*          partial = (float*)(wsb + 8404992);            //    8192 B
        int*            idx     = (int*)(wsb + 8413184);              //  262144 B

        norms_kernel<<<NE / 256, 256, 0, stream>>>(embed, norms);
        prep_kernel<<<dim3(64, 8), 256, 0, stream>>>(embed, ehf, el);
        vq_main<<<512, 256, 0, stream>>>(x, ehf, el, norms, out_idx, idx);
        gather_kernel<<<2048, 256, 0, stream>>>(x, ehf, el, idx, out_q, partial);
        diff_kernel<<<1, 256, 0, stream>>>(partial, out_diff);
    } else {
        float* norms   = (float*)wsb;            // 16384 B
        float* partial = norms + NE;             //  8192 B
        norms_kernel<<<NE / 256, 256, 0, stream>>>(embed, norms);
        vq_kernel_fb<<<NROWS / BM, 256, 0, stream>>>(x, embed, norms, out_q, out_idx, partial);
        diff_kernel<<<1, 256, 0, stream>>>(partial, out_diff);
    }
}

// Round 10
// 416.181 us; speedup vs baseline: 1.1292x; 1.1292x over previous
//
#include <hip/hip_runtime.h>
#include <math.h>

#define DIM 512
#define NE 4096
#define NROWS 65536
#define MARGIN 1.0f            // truncated-gap gate: true gap > 0.75 ≈ 15 sigma of scan noise

typedef __attribute__((ext_vector_type(8))) short short8;
typedef __attribute__((ext_vector_type(4))) float f32x4;

// ---- bf16 helpers (round-to-nearest-even) ----
__device__ inline unsigned short f2bf(float f) {
    union { float f; unsigned int u; } v; v.f = f;
    unsigned int u = v.u;
    return (unsigned short)((u + 0x7fffu + ((u >> 16) & 1u)) >> 16);
}
__device__ inline float bf2f(unsigned short h) {
    union { unsigned int u; float f; } v; v.u = ((unsigned int)h) << 16;
    return v.f;
}
__device__ inline short hi_bf(float f) { return (short)f2bf(f); }

// fragment-ordered short index for hi image, 32-code panels (R9, proven):
//   panel p=e>>5, section sec=(d>>5)*2+((e>>4)&1), granule g=((d>>3)&3)*16+(e&15), elem d&7
__device__ __forceinline__ size_t ehf_idx(int e, int d) {
    return (size_t)(e >> 5) * 16384 +
           (size_t)(((((d >> 5) * 2 + ((e >> 4) & 1)) * 64) + ((d >> 3) & 3) * 16 + (e & 15)) * 8 + (d & 7));
}

// ---- async global->LDS (16B/lane; LDS dest = wave-uniform base + lane*16) ----
typedef __attribute__((address_space(1))) const void gconst_t;
typedef __attribute__((address_space(3))) void ldsv_t;
__device__ __forceinline__ void gload_lds16(const void* g, void* l) {
    __builtin_amdgcn_global_load_lds((gconst_t*)g, (ldsv_t*)l, 16, 0, 0);
}

// ---------------- codebook column norms (fp32, proven R1) ----------------
__global__ void norms_kernel(const float* __restrict__ embed, float* __restrict__ norms) {
    int e = blockIdx.x * blockDim.x + threadIdx.x;
    if (e < NE) {
        float s = 0.f;
        #pragma unroll 8
        for (int d = 0; d < DIM; ++d) {
            float v = embed[(size_t)d * NE + e];
            s += v * v;
        }
        norms[e] = s;
    }
}

// ---------------- transpose + hi/lo split (R9, proven) ----------------
__global__ void prep_kernel(const float* __restrict__ embed,
                            unsigned short* __restrict__ ehf,
                            unsigned short* __restrict__ el) {
    __shared__ float t[64][65];
    const int tid = threadIdx.x;                 // 256
    const int e0 = blockIdx.x * 64;              // 64 blocks
    const int d0 = blockIdx.y * 64;              // 8 blocks
    for (int i = tid; i < 4096; i += 256) {
        int r = i >> 6, c = i & 63;              // r: d, c: e  (coalesced in e)
        t[r][c] = embed[(size_t)(d0 + r) * NE + e0 + c];
    }
    __syncthreads();
    for (int i = tid; i < 4096; i += 256) {
        int r = i >> 6, c = i & 63;              // r: e, c: d
        float v = t[c][r];
        int e = e0 + r, d = d0 + c;
        unsigned short h = f2bf(v);
        ehf[ehf_idx(e, d)] = h;
        el[(size_t)e * 512 + d] = f2bf(v - bf2f(h));
    }
}

// ---------------- main: 1-pass bf16 MFMA scan, deferred epilogue (2-ct unroll),
//                  packed-u32 per-lane top-2 -> global top-4 -> margin-gated rescore ----
__global__ __launch_bounds__(256, 2) void vq_main(
        const float* __restrict__ x,
        const unsigned short* __restrict__ ehf,
        const unsigned short* __restrict__ el,
        const float* __restrict__ norms,
        float* __restrict__ out_idx,
        int* __restrict__ idx_ws) {

    __shared__ unsigned short ph[2][32 * 512];   // 2 x 32768 B, fragment order
    __shared__ int   bi4[128][4];
    __shared__ float bgap[128];

    const int tid = threadIdx.x;
    const int w   = tid >> 6;                    // wave 0..3
    const int l   = tid & 63;
    const int lr  = l & 15;
    const int lg  = l >> 4;
    const int row0 = blockIdx.x * 128;

    // ---- A fragments: 2 rowsets x 16 ks, single bf16 (R9, proven) ----
    short8 a[2][16];
    #pragma unroll
    for (int s = 0; s < 2; ++s) {
        const float* xp = x + (size_t)(row0 + w * 32 + s * 16 + lr) * DIM + lg * 8;
        #pragma unroll
        for (int ks = 0; ks < 16; ++ks) {
            float4 u  = *(const float4*)(xp + ks * 32);
            float4 v2 = *(const float4*)(xp + ks * 32 + 4);
            short8 h;
            h[0]=hi_bf(u.x);  h[1]=hi_bf(u.y);  h[2]=hi_bf(u.z);  h[3]=hi_bf(u.w);
            h[4]=hi_bf(v2.x); h[5]=hi_bf(v2.y); h[6]=hi_bf(v2.z); h[7]=hi_bf(v2.w);
            a[s][ks] = h;
        }
    }

    // packed top-2 per slot: key = (score_bits & ~0xFFF) | e  (scores provably > 0)
    unsigned p1[2][4], p2[2][4];
    #pragma unroll
    for (int s = 0; s < 2; ++s)
        #pragma unroll
        for (int r = 0; r < 4; ++r) { p1[s][r] = 0xFFFFFFFFu; p2[s][r] = 0xFFFFFFFFu; }

    f32x4 accA[2][2], accB[2][2];

    #define STAGE_PANEL(p, b)                                                      \
    {                                                                              \
        const unsigned short* gsrc = ehf + (size_t)(p) * 16384 + w * 4096 + l * 8; \
        unsigned short* ldst = &ph[b][w * 4096];                                   \
        _Pragma("unroll")                                                          \
        for (int j = 0; j < 8; ++j)                                                \
            gload_lds16(gsrc + j * 512, ldst + j * 512);                           \
    }

    #define MFMA_PANEL(ACC, BUF)                                                   \
    {                                                                              \
        _Pragma("unroll")                                                          \
        for (int s = 0; s < 2; ++s)                                                \
            _Pragma("unroll")                                                      \
            for (int cb = 0; cb < 2; ++cb) ACC[s][cb] = (f32x4){0.f,0.f,0.f,0.f};  \
        _Pragma("unroll")                                                          \
        for (int ks = 0; ks < 16; ++ks) {                                          \
            _Pragma("unroll")                                                      \
            for (int cb = 0; cb < 2; ++cb) {                                       \
                short8 bh = *(const short8*)&ph[BUF][(ks * 2 + cb) * 512 + l * 8]; \
                ACC[0][cb] = __builtin_amdgcn_mfma_f32_16x16x32_bf16(a[0][ks], bh, ACC[0][cb], 0, 0, 0); \
                ACC[1][cb] = __builtin_amdgcn_mfma_f32_16x16x32_bf16(a[1][ks], bh, ACC[1][cb], 0, 0, 0); \
            }                                                                      \
        }                                                                          \
    }

    #define EPIL_PANEL(ACC, PANEL)                                                 \
    {                                                                              \
        _Pragma("unroll")                                                          \
        for (int cb = 0; cb < 2; ++cb) {                                           \
            int e = (PANEL) * 32 + cb * 16 + lr;                                   \
            float nrm = norms[e];                                                  \
            _Pragma("unroll")                                                      \
            for (int s = 0; s < 2; ++s)                                            \
                _Pragma("unroll")                                                  \
                for (int r = 0; r < 4; ++r) {                                      \
                    float sv = fmaf(-2.0f, ACC[s][cb][r], nrm);                    \
                    unsigned pv = (__float_as_uint(sv) & 0xFFFFF000u) | (unsigned)e; \
                    unsigned t = max(p1[s][r], pv);                                \
                    p1[s][r] = min(p1[s][r], pv);                                  \
                    p2[s][r] = min(p2[s][r], t);                                   \
                }                                                                  \
        }                                                                          \
    }

    // prologue: panel 0
    STAGE_PANEL(0, 0)
    __syncthreads();
    STAGE_PANEL(1, 1)
    MFMA_PANEL(accA, 0)
    __syncthreads();

    // main: 2 panels per iteration; epilogue of the previous acc overlaps current MFMA
    #pragma unroll 1
    for (int i = 1; i < 127; i += 2) {
        // odd panel i in buf1
        STAGE_PANEL(i + 1, 0)
        MFMA_PANEL(accB, 1)
        EPIL_PANEL(accA, i - 1)
        __syncthreads();
        // even panel i+1 in buf0
        if (i + 2 < 128) STAGE_PANEL(i + 2, 1)
        MFMA_PANEL(accA, 0)
        EPIL_PANEL(accB, i)
        __syncthreads();
    }
    // tail: panel 127 in buf1
    MFMA_PANEL(accB, 1)
    EPIL_PANEL(accA, 126)
    EPIL_PANEL(accB, 127)

    #undef STAGE_PANEL
    #undef MFMA_PANEL
    #undef EPIL_PANEL

    // ---- per-slot: merge per-lane packed top-2 into global top-4 (umin/umax net) ----
    #pragma unroll
    for (int s = 0; s < 2; ++s) {
        #pragma unroll
        for (int r = 0; r < 4; ++r) {
            unsigned av[4] = { p1[s][r], p2[s][r], 0xFFFFFFFFu, 0xFFFFFFFFu };
            #pragma unroll
            for (int m = 1; m < 16; m <<= 1) {
                unsigned bv[4];
                #pragma unroll
                for (int q = 0; q < 4; ++q)
                    bv[q] = (unsigned)__shfl_xor((int)av[q], m, 64);
                unsigned cv[4];
                #pragma unroll
                for (int q = 0; q < 4; ++q) cv[q] = min(av[q], bv[3 - q]);
                #define CE(A,B) { unsigned lo = min(cv[A], cv[B]); unsigned hi = max(cv[A], cv[B]); cv[A] = lo; cv[B] = hi; }
                CE(0,2) CE(1,3) CE(0,1) CE(2,3)
                #undef CE
                #pragma unroll
                for (int q = 0; q < 4; ++q) av[q] = cv[q];
            }
            if (lr == 0) {
                int rowloc = w * 32 + s * 16 + lg * 4 + r;
                #pragma unroll
                for (int q = 0; q < 4; ++q) bi4[rowloc][q] = (int)av[q];
                float v0 = __uint_as_float(av[0] & 0xFFFFF000u);
                float v1 = __uint_as_float(av[1] & 0xFFFFF000u);
                bgap[rowloc] = v1 - v0;
            }
        }
    }
    __syncthreads();

    // ---- margin-gated exact rescore (x fp32, e = hi+lo) of the 4 candidates ----
    #pragma unroll 1
    for (int rr = 0; rr < 32; ++rr) {
        int rowloc = w * 32 + rr;
        int grow = row0 + rowloc;
        float gap = bgap[rowloc];
        int c0 = bi4[rowloc][0] & (NE - 1);
        if (gap > MARGIN) {
            if (l == 0) { out_idx[grow] = (float)c0; idx_ws[grow] = c0; }
            continue;
        }
        int cand[4];
        cand[0] = c0;
        cand[1] = bi4[rowloc][1] & (NE - 1);
        cand[2] = bi4[rowloc][2] & (NE - 1);
        cand[3] = bi4[rowloc][3] & (NE - 1);

        const float* xr = x + (size_t)grow * DIM + l * 8;
        float4 xa = *(const float4*)xr, xb = *(const float4*)(xr + 4);
        float xv[8] = {xa.x, xa.y, xa.z, xa.w, xb.x, xb.y, xb.z, xb.w};

        float d[4];
        #pragma unroll
        for (int q = 0; q < 4; ++q) {
            uint4 hv = *(const uint4*)&ehf[ehf_idx(cand[q], l * 8)];
            uint4 lv = *(const uint4*)&el[(size_t)cand[q] * 512 + l * 8];
            const unsigned short* hp = (const unsigned short*)&hv;
            const unsigned short* lp = (const unsigned short*)&lv;
            float acc = 0.f;
            #pragma unroll
            for (int j = 0; j < 8; ++j) acc += xv[j] * (bf2f(hp[j]) + bf2f(lp[j]));
            d[q] = acc;
        }
        #pragma unroll
        for (int m = 32; m >= 1; m >>= 1) {
            #pragma unroll
            for (int q = 0; q < 4; ++q) d[q] += __shfl_xor(d[q], m, 64);
        }
        if (l == 0) {
            float bs = norms[cand[0]] - 2.0f * d[0];
            int   bi = cand[0];
            #pragma unroll
            for (int q = 1; q < 4; ++q) {
                float sq = norms[cand[q]] - 2.0f * d[q];
                if (sq < bs || (sq == bs && cand[q] < bi)) { bs = sq; bi = cand[q]; }
            }
            out_idx[grow] = (float)bi;
            idx_ws[grow] = bi;
        }
    }
}

// ---------------- gather + diff partials (hi fragment-ordered + lo linear; proven) ----------------
__global__ void gather_kernel(const float* __restrict__ x,
                              const unsigned short* __restrict__ ehf,
                              const unsigned short* __restrict__ el,
                              const int* __restrict__ idx, float* __restrict__ out_q,
                              float* __restrict__ partial) {
    __shared__ float red[256];
    const int tid = threadIdx.x;
    float local = 0.f;
    #pragma unroll 1
    for (int j = 0; j < 8; ++j) {
        int o8 = blockIdx.x * 2048 + j * 256 + tid;   // octet unit
        int r  = o8 >> 6;                             // 64 octets per row
        int c8 = o8 & 63;
        int e  = idx[r];
        uint4 hv = *(const uint4*)&ehf[ehf_idx(e, c8 * 8)];
        uint4 lv = *(const uint4*)&el[(size_t)e * 512 + c8 * 8];
        const unsigned short* hp = (const unsigned short*)&hv;
        const unsigned short* lp = (const unsigned short*)&lv;
        float q[8];
        #pragma unroll
        for (int k = 0; k < 8; ++k) q[k] = bf2f(hp[k]) + bf2f(lp[k]);
        float4 xa = *(const float4*)&x[(size_t)r * DIM + c8 * 8];
        float4 xb = *(const float4*)&x[(size_t)r * DIM + c8 * 8 + 4];
        *(float4*)&out_q[(size_t)r * DIM + c8 * 8]     = make_float4(q[0], q[1], q[2], q[3]);
        *(float4*)&out_q[(size_t)r * DIM + c8 * 8 + 4] = make_float4(q[4], q[5], q[6], q[7]);
        float xs[8] = {xa.x, xa.y, xa.z, xa.w, xb.x, xb.y, xb.z, xb.w};
        #pragma unroll
        for (int k = 0; k < 8; ++k) { float t = q[k] - xs[k]; local += t * t; }
    }
    red[tid] = local;
    __syncthreads();
    for (int s = 128; s > 0; s >>= 1) {
        if (tid < s) red[tid] += red[tid + s];
        __syncthreads();
    }
    if (tid == 0) partial[blockIdx.x] = red[0];
}

// ---------------- deterministic diff reduction ----------------
__global__ void diff_kernel(const float* __restrict__ partial, float* __restrict__ out_diff) {
    __shared__ float red[256];
    float s = 0.f;
    for (int i = threadIdx.x; i < 2048; i += 256) s += partial[i];
    red[threadIdx.x] = s;
    __syncthreads();
    for (int st = 128; st > 0; st >>= 1) {
        if (threadIdx.x < st) red[threadIdx.x] += red[threadIdx.x + st];
        __syncthreads();
    }
    if (threadIdx.x == 0)
        out_diff[0] = red[0] * (1.0f / ((float)NROWS * (float)DIM));
}

// ================= fallback path (R1, proven; needs only 24 KB ws) =================
#define BM 32
#define BN 64
#define BK 16
__global__ __launch_bounds__(256) void vq_kernel_fb(
        const float* __restrict__ x, const float* __restrict__ embed,
        const float* __restrict__ norms, float* __restrict__ out_q,
        float* __restrict__ out_idx, float* __restrict__ partial) {
    __shared__ float xs[BM][BK + 1];
    __shared__ float es[BK][BN];
    __shared__ float rv[BM][17];
    __shared__ int   ri[BM][17];
    __shared__ float bestv[BM];
    __shared__ int   besti[BM];
    __shared__ float red[256];
    const int tid = threadIdx.x;
    const int tc  = tid & 15;
    const int tr  = tid >> 4;
    const int row0 = blockIdx.x * BM;
    if (tid < BM) { bestv[tid] = INFINITY; besti[tid] = 0; }
    __syncthreads();
    for (int ct = 0; ct < NE / BN; ++ct) {
        float acc[2][4] = {{0.f,0.f,0.f,0.f},{0.f,0.f,0.f,0.f}};
        for (int k0 = 0; k0 < DIM; k0 += BK) {
            {
                int r = tid >> 3;
                int k = (tid & 7) * 2;
                const float* src = &x[(size_t)(row0 + r) * DIM + k0 + k];
                xs[r][k] = src[0]; xs[r][k + 1] = src[1];
            }
            {
                int r = tid >> 4;
                int c = (tid & 15) * 4;
                float4 v = *(const float4*)&embed[(size_t)(k0 + r) * NE + ct * BN + c];
                *(float4*)&es[r][c] = v;
            }
            __syncthreads();
            #pragma unroll
            for (int kk = 0; kk < BK; ++kk) {
                float a0 = xs[tr * 2 + 0][kk];
                float a1 = xs[tr * 2 + 1][kk];
                float4 b = *(const float4*)&es[kk][tc * 4];
                acc[0][0] += a0 * b.x; acc[0][1] += a0 * b.y;
                acc[0][2] += a0 * b.z; acc[0][3] += a0 * b.w;
                acc[1][0] += a1 * b.x; acc[1][1] += a1 * b.y;
                acc[1][2] += a1 * b.z; acc[1][3] += a1 * b.w;
            }
            __syncthreads();
        }
        #pragma unroll
        for (int i = 0; i < 2; ++i) {
            float bv = INFINITY; int bj = 0;
            #pragma unroll
            for (int j = 0; j < 4; ++j) {
                int e = ct * BN + tc * 4 + j;
                float s = norms[e] - 2.0f * acc[i][j];
                if (s < bv) { bv = s; bj = e; }
            }
            rv[tr * 2 + i][tc] = bv; ri[tr * 2 + i][tc] = bj;
        }
        __syncthreads();
        if (tid < BM) {
            float bv = bestv[tid]; int bi = besti[tid];
            #pragma unroll
            for (int t = 0; t < 16; ++t) {
                float v = rv[tid][t];
                if (v < bv) { bv = v; bi = ri[tid][t]; }
            }
            bestv[tid] = bv; besti[tid] = bi;
        }
        __syncthreads();
    }
    if (tid < BM) out_idx[row0 + tid] = (float)besti[tid];
    __syncthreads();
    float local = 0.f;
    for (int i = tid; i < BM * DIM; i += 256) {
        int r = i >> 9;
        int d = i & (DIM - 1);
        int e = besti[r];
        float q  = embed[(size_t)d * NE + e];
        float xv = x[(size_t)(row0 + r) * DIM + d];
        out_q[(size_t)(row0 + r) * DIM + d] = q;
        float t = q - xv;
        local += t * t;
    }
    red[tid] = local;
    __syncthreads();
    for (int s = 128; s > 0; s >>= 1) {
        if (tid < s) red[tid] += red[tid + s];
        __syncthreads();
    }
    if (tid == 0) partial[blockIdx.x] = red[0];
}

extern "C" void kernel_launch(void* const* d_in, const int* in_sizes, int n_in,
                              void* d_out, int out_size, void* d_ws, size_t ws_size,
                              hipStream_t stream) {
    (void)in_sizes; (void)n_in; (void)out_size;
    const float* x     = (const float*)d_in[0];
    const float* embed = (const float*)d_in[1];

    float* out      = (float*)d_out;
    float* out_q    = out;
    float* out_diff = out + (size_t)NROWS * DIM;
    float* out_idx  = out_diff + 1;

    const size_t NEED = 4194304ull * 2 + 16384 + 8192 + 262144;  // ehf+el+norms+partial+idx

    char* wsb = (char*)d_ws;
    if (ws_size >= NEED) {
        unsigned short* ehf     = (unsigned short*)wsb;               // 4194304 B
        unsigned short* el      = (unsigned short*)(wsb + 4194304);   // 4194304 B
        float*          norms   = (float*)(wsb + 8388608);            //   16384 B
        float*          partial = (float*)(wsb + 8404992);            //    8192 B
        int*            idx     = (int*)(wsb + 8413184);              //  262144 B

        norms_kernel<<<NE / 256, 256, 0, stream>>>(embed, norms);
        prep_kernel<<<dim3(64, 8), 256, 0, stream>>>(embed, ehf, el);
        vq_main<<<512, 256, 0, stream>>>(x, ehf, el, norms, out_idx, idx);
        gather_kernel<<<2048, 256, 0, stream>>>(x, ehf, el, idx, out_q, partial);
        diff_kernel<<<1, 256, 0, stream>>>(partial, out_diff);
    } else {
        float* norms   = (float*)wsb;            // 16384 B
        float* partial = norms + NE;             //  8192 B
        norms_kernel<<<NE / 256, 256, 0, stream>>>(embed, norms);
        vq_kernel_fb<<<NROWS / BM, 256, 0, stream>>>(x, embed, norms, out_q, out_idx, partial);
        diff_kernel<<<1, 256, 0, stream>>>(partial, out_diff);
    }
}

// Round 11
// 392.562 us; speedup vs baseline: 1.1971x; 1.0602x over previous
//
#include <hip/hip_runtime.h>
#include <math.h>

#define DIM 512
#define NE 4096
#define NROWS 65536
#define MARGIN 1.0f            // truncated-gap gate: true gap > 0.75 ≈ 15 sigma of scan noise

typedef __attribute__((ext_vector_type(8))) short short8;
typedef __attribute__((ext_vector_type(4))) float f32x4;

// ---- bf16 helpers (round-to-nearest-even) ----
__device__ inline unsigned short f2bf(float f) {
    union { float f; unsigned int u; } v; v.f = f;
    unsigned int u = v.u;
    return (unsigned short)((u + 0x7fffu + ((u >> 16) & 1u)) >> 16);
}
__device__ inline float bf2f(unsigned short h) {
    union { unsigned int u; float f; } v; v.u = ((unsigned int)h) << 16;
    return v.f;
}
__device__ inline short hi_bf(float f) { return (short)f2bf(f); }

// fragment-ordered short index for hi image, 32-code panels (R9, proven):
//   panel p=e>>5, section sec=(d>>5)*2+((e>>4)&1), granule g=((d>>3)&3)*16+(e&15), elem d&7
__device__ __forceinline__ size_t ehf_idx(int e, int d) {
    return (size_t)(e >> 5) * 16384 +
           (size_t)(((((d >> 5) * 2 + ((e >> 4) & 1)) * 64) + ((d >> 3) & 3) * 16 + (e & 15)) * 8 + (d & 7));
}

// ---- async global->LDS (16B/lane; LDS dest = wave-uniform base + lane*16) ----
typedef __attribute__((address_space(1))) const void gconst_t;
typedef __attribute__((address_space(3))) void ldsv_t;
__device__ __forceinline__ void gload_lds16(const void* g, void* l) {
    __builtin_amdgcn_global_load_lds((gconst_t*)g, (ldsv_t*)l, 16, 0, 0);
}

// ---------------- codebook column norms (fp32, proven R1) ----------------
__global__ void norms_kernel(const float* __restrict__ embed, float* __restrict__ norms) {
    int e = blockIdx.x * blockDim.x + threadIdx.x;
    if (e < NE) {
        float s = 0.f;
        #pragma unroll 8
        for (int d = 0; d < DIM; ++d) {
            float v = embed[(size_t)d * NE + e];
            s += v * v;
        }
        norms[e] = s;
    }
}

// ---------------- transpose + hi/lo split (R9, proven) ----------------
__global__ void prep_kernel(const float* __restrict__ embed,
                            unsigned short* __restrict__ ehf,
                            unsigned short* __restrict__ el) {
    __shared__ float t[64][65];
    const int tid = threadIdx.x;                 // 256
    const int e0 = blockIdx.x * 64;              // 64 blocks
    const int d0 = blockIdx.y * 64;              // 8 blocks
    for (int i = tid; i < 4096; i += 256) {
        int r = i >> 6, c = i & 63;              // r: d, c: e  (coalesced in e)
        t[r][c] = embed[(size_t)(d0 + r) * NE + e0 + c];
    }
    __syncthreads();
    for (int i = tid; i < 4096; i += 256) {
        int r = i >> 6, c = i & 63;              // r: e, c: d
        float v = t[c][r];
        int e = e0 + r, d = d0 + c;
        unsigned short h = f2bf(v);
        ehf[ehf_idx(e, d)] = h;
        el[(size_t)e * 512 + d] = f2bf(v - bf2f(h));
    }
}

// ---------------- main: 1-pass bf16 MFMA scan, deferred epilogue (2-ct unroll),
//                  distance-2 B prefetch, packed-u32 top-2 -> top-4 -> rescore ----
__global__ __launch_bounds__(256, 2) void vq_main(
        const float* __restrict__ x,
        const unsigned short* __restrict__ ehf,
        const unsigned short* __restrict__ el,
        const float* __restrict__ norms,
        float* __restrict__ out_idx,
        int* __restrict__ idx_ws) {

    __shared__ unsigned short ph[2][32 * 512];   // 2 x 32768 B, fragment order
    __shared__ int   bi4[128][4];
    __shared__ float bgap[128];

    const int tid = threadIdx.x;
    const int w   = tid >> 6;                    // wave 0..3
    const int l   = tid & 63;
    const int lr  = l & 15;
    const int lg  = l >> 4;
    const int row0 = blockIdx.x * 128;

    // ---- A fragments: 2 rowsets x 16 ks, single bf16 (R9, proven) ----
    short8 a[2][16];
    #pragma unroll
    for (int s = 0; s < 2; ++s) {
        const float* xp = x + (size_t)(row0 + w * 32 + s * 16 + lr) * DIM + lg * 8;
        #pragma unroll
        for (int ks = 0; ks < 16; ++ks) {
            float4 u  = *(const float4*)(xp + ks * 32);
            float4 v2 = *(const float4*)(xp + ks * 32 + 4);
            short8 h;
            h[0]=hi_bf(u.x);  h[1]=hi_bf(u.y);  h[2]=hi_bf(u.z);  h[3]=hi_bf(u.w);
            h[4]=hi_bf(v2.x); h[5]=hi_bf(v2.y); h[6]=hi_bf(v2.z); h[7]=hi_bf(v2.w);
            a[s][ks] = h;
        }
    }

    // packed top-2 per slot: key = (score_bits & ~0xFFF) | e  (scores provably > 0)
    unsigned p1[2][4], p2[2][4];
    #pragma unroll
    for (int s = 0; s < 2; ++s)
        #pragma unroll
        for (int r = 0; r < 4; ++r) { p1[s][r] = 0xFFFFFFFFu; p2[s][r] = 0xFFFFFFFFu; }

    f32x4 accA[2][2], accB[2][2];

    #define STAGE_PANEL(p, b)                                                      \
    {                                                                              \
        const unsigned short* gsrc = ehf + (size_t)(p) * 16384 + w * 4096 + l * 8; \
        unsigned short* ldst = &ph[b][w * 4096];                                   \
        _Pragma("unroll")                                                          \
        for (int j = 0; j < 8; ++j)                                                \
            gload_lds16(gsrc + j * 512, ldst + j * 512);                           \
    }

    // distance-2 software prefetch of B fragments: reads for ks+2 issued before
    // the MFMAs of ks; bh[3][2] rotation, all indices static after full unroll.
    #define MFMA_PANEL(ACC, BUF)                                                   \
    {                                                                              \
        short8 bh[3][2];                                                           \
        bh[0][0] = *(const short8*)&ph[BUF][(0 * 2 + 0) * 512 + l * 8];            \
        bh[0][1] = *(const short8*)&ph[BUF][(0 * 2 + 1) * 512 + l * 8];            \
        bh[1][0] = *(const short8*)&ph[BUF][(1 * 2 + 0) * 512 + l * 8];            \
        bh[1][1] = *(const short8*)&ph[BUF][(1 * 2 + 1) * 512 + l * 8];            \
        _Pragma("unroll")                                                          \
        for (int s = 0; s < 2; ++s)                                                \
            _Pragma("unroll")                                                      \
            for (int cb = 0; cb < 2; ++cb) ACC[s][cb] = (f32x4){0.f,0.f,0.f,0.f};  \
        _Pragma("unroll")                                                          \
        for (int ks = 0; ks < 16; ++ks) {                                          \
            if (ks < 14) {                                                         \
                bh[(ks + 2) % 3][0] = *(const short8*)&ph[BUF][((ks + 2) * 2 + 0) * 512 + l * 8]; \
                bh[(ks + 2) % 3][1] = *(const short8*)&ph[BUF][((ks + 2) * 2 + 1) * 512 + l * 8]; \
            }                                                                      \
            _Pragma("unroll")                                                      \
            for (int cb = 0; cb < 2; ++cb) {                                       \
                ACC[0][cb] = __builtin_amdgcn_mfma_f32_16x16x32_bf16(a[0][ks], bh[ks % 3][cb], ACC[0][cb], 0, 0, 0); \
                ACC[1][cb] = __builtin_amdgcn_mfma_f32_16x16x32_bf16(a[1][ks], bh[ks % 3][cb], ACC[1][cb], 0, 0, 0); \
            }                                                                      \
        }                                                                          \
    }

    #define EPIL_PANEL(ACC, PANEL)                                                 \
    {                                                                              \
        _Pragma("unroll")                                                          \
        for (int cb = 0; cb < 2; ++cb) {                                           \
            int e = (PANEL) * 32 + cb * 16 + lr;                                   \
            float nrm = norms[e];                                                  \
            _Pragma("unroll")                                                      \
            for (int s = 0; s < 2; ++s)                                            \
                _Pragma("unroll")                                                  \
                for (int r = 0; r < 4; ++r) {                                      \
                    float sv = fmaf(-2.0f, ACC[s][cb][r], nrm);                    \
                    unsigned pv = (__float_as_uint(sv) & 0xFFFFF000u) | (unsigned)e; \
                    unsigned t = max(p1[s][r], pv);                                \
                    p1[s][r] = min(p1[s][r], pv);                                  \
                    p2[s][r] = min(p2[s][r], t);                                   \
                }                                                                  \
        }                                                                          \
    }

    // prologue: panel 0
    STAGE_PANEL(0, 0)
    __syncthreads();
    STAGE_PANEL(1, 1)
    MFMA_PANEL(accA, 0)
    __syncthreads();

    // main: 2 panels per iteration; epilogue of the previous acc overlaps current MFMA
    #pragma unroll 1
    for (int i = 1; i < 127; i += 2) {
        // odd panel i in buf1
        STAGE_PANEL(i + 1, 0)
        MFMA_PANEL(accB, 1)
        EPIL_PANEL(accA, i - 1)
        __syncthreads();
        // even panel i+1 in buf0
        if (i + 2 < 128) STAGE_PANEL(i + 2, 1)
        MFMA_PANEL(accA, 0)
        EPIL_PANEL(accB, i)
        __syncthreads();
    }
    // tail: panel 127 in buf1
    MFMA_PANEL(accB, 1)
    EPIL_PANEL(accA, 126)
    EPIL_PANEL(accB, 127)

    #undef STAGE_PANEL
    #undef MFMA_PANEL
    #undef EPIL_PANEL

    // ---- per-slot: merge per-lane packed top-2 into global top-4 (umin/umax net) ----
    #pragma unroll
    for (int s = 0; s < 2; ++s) {
        #pragma unroll
        for (int r = 0; r < 4; ++r) {
            unsigned av[4] = { p1[s][r], p2[s][r], 0xFFFFFFFFu, 0xFFFFFFFFu };
            #pragma unroll
            for (int m = 1; m < 16; m <<= 1) {
                unsigned bv[4];
                #pragma unroll
                for (int q = 0; q < 4; ++q)
                    bv[q] = (unsigned)__shfl_xor((int)av[q], m, 64);
                unsigned cv[4];
                #pragma unroll
                for (int q = 0; q < 4; ++q) cv[q] = min(av[q], bv[3 - q]);
                #define CE(A,B) { unsigned lo = min(cv[A], cv[B]); unsigned hi = max(cv[A], cv[B]); cv[A] = lo; cv[B] = hi; }
                CE(0,2) CE(1,3) CE(0,1) CE(2,3)
                #undef CE
                #pragma unroll
                for (int q = 0; q < 4; ++q) av[q] = cv[q];
            }
            if (lr == 0) {
                int rowloc = w * 32 + s * 16 + lg * 4 + r;
                #pragma unroll
                for (int q = 0; q < 4; ++q) bi4[rowloc][q] = (int)av[q];
                float v0 = __uint_as_float(av[0] & 0xFFFFF000u);
                float v1 = __uint_as_float(av[1] & 0xFFFFF000u);
                bgap[rowloc] = v1 - v0;
            }
        }
    }
    __syncthreads();

    // ---- margin-gated exact rescore (x fp32, e = hi+lo) of the 4 candidates ----
    #pragma unroll 1
    for (int rr = 0; rr < 32; ++rr) {
        int rowloc = w * 32 + rr;
        int grow = row0 + rowloc;
        float gap = bgap[rowloc];
        int c0 = bi4[rowloc][0] & (NE - 1);
        if (gap > MARGIN) {
            if (l == 0) { out_idx[grow] = (float)c0; idx_ws[grow] = c0; }
            continue;
        }
        int cand[4];
        cand[0] = c0;
        cand[1] = bi4[rowloc][1] & (NE - 1);
        cand[2] = bi4[rowloc][2] & (NE - 1);
        cand[3] = bi4[rowloc][3] & (NE - 1);

        const float* xr = x + (size_t)grow * DIM + l * 8;
        float4 xa = *(const float4*)xr, xb = *(const float4*)(xr + 4);
        float xv[8] = {xa.x, xa.y, xa.z, xa.w, xb.x, xb.y, xb.z, xb.w};

        float d[4];
        #pragma unroll
        for (int q = 0; q < 4; ++q) {
            uint4 hv = *(const uint4*)&ehf[ehf_idx(cand[q], l * 8)];
            uint4 lv = *(const uint4*)&el[(size_t)cand[q] * 512 + l * 8];
            const unsigned short* hp = (const unsigned short*)&hv;
            const unsigned short* lp = (const unsigned short*)&lv;
            float acc = 0.f;
            #pragma unroll
            for (int j = 0; j < 8; ++j) acc += xv[j] * (bf2f(hp[j]) + bf2f(lp[j]));
            d[q] = acc;
        }
        #pragma unroll
        for (int m = 32; m >= 1; m >>= 1) {
            #pragma unroll
            for (int q = 0; q < 4; ++q) d[q] += __shfl_xor(d[q], m, 64);
        }
        if (l == 0) {
            float bs = norms[cand[0]] - 2.0f * d[0];
            int   bi = cand[0];
            #pragma unroll
            for (int q = 1; q < 4; ++q) {
                float sq = norms[cand[q]] - 2.0f * d[q];
                if (sq < bs || (sq == bs && cand[q] < bi)) { bs = sq; bi = cand[q]; }
            }
            out_idx[grow] = (float)bi;
            idx_ws[grow] = bi;
        }
    }
}

// ---------------- gather + diff partials (hi fragment-ordered + lo linear; proven) ----------------
__global__ void gather_kernel(const float* __restrict__ x,
                              const unsigned short* __restrict__ ehf,
                              const unsigned short* __restrict__ el,
                              const int* __restrict__ idx, float* __restrict__ out_q,
                              float* __restrict__ partial) {
    __shared__ float red[256];
    const int tid = threadIdx.x;
    float local = 0.f;
    #pragma unroll 1
    for (int j = 0; j < 8; ++j) {
        int o8 = blockIdx.x * 2048 + j * 256 + tid;   // octet unit
        int r  = o8 >> 6;                             // 64 octets per row
        int c8 = o8 & 63;
        int e  = idx[r];
        uint4 hv = *(const uint4*)&ehf[ehf_idx(e, c8 * 8)];
        uint4 lv = *(const uint4*)&el[(size_t)e * 512 + c8 * 8];
        const unsigned short* hp = (const unsigned short*)&hv;
        const unsigned short* lp = (const unsigned short*)&lv;
        float q[8];
        #pragma unroll
        for (int k = 0; k < 8; ++k) q[k] = bf2f(hp[k]) + bf2f(lp[k]);
        float4 xa = *(const float4*)&x[(size_t)r * DIM + c8 * 8];
        float4 xb = *(const float4*)&x[(size_t)r * DIM + c8 * 8 + 4];
        *(float4*)&out_q[(size_t)r * DIM + c8 * 8]     = make_float4(q[0], q[1], q[2], q[3]);
        *(float4*)&out_q[(size_t)r * DIM + c8 * 8 + 4] = make_float4(q[4], q[5], q[6], q[7]);
        float xs[8] = {xa.x, xa.y, xa.z, xa.w, xb.x, xb.y, xb.z, xb.w};
        #pragma unroll
        for (int k = 0; k < 8; ++k) { float t = q[k] - xs[k]; local += t * t; }
    }
    red[tid] = local;
    __syncthreads();
    for (int s = 128; s > 0; s >>= 1) {
        if (tid < s) red[tid] += red[tid + s];
        __syncthreads();
    }
    if (tid == 0) partial[blockIdx.x] = red[0];
}

// ---------------- deterministic diff reduction ----------------
__global__ void diff_kernel(const float* __restrict__ partial, float* __restrict__ out_diff) {
    __shared__ float red[256];
    float s = 0.f;
    for (int i = threadIdx.x; i < 2048; i += 256) s += partial[i];
    red[threadIdx.x] = s;
    __syncthreads();
    for (int st = 128; st > 0; st >>= 1) {
        if (threadIdx.x < st) red[threadIdx.x] += red[threadIdx.x + st];
        __syncthreads();
    }
    if (threadIdx.x == 0)
        out_diff[0] = red[0] * (1.0f / ((float)NROWS * (float)DIM));
}

// ================= fallback path (R1, proven; needs only 24 KB ws) =================
#define BM 32
#define BN 64
#define BK 16
__global__ __launch_bounds__(256) void vq_kernel_fb(
        const float* __restrict__ x, const float* __restrict__ embed,
        const float* __restrict__ norms, float* __restrict__ out_q,
        float* __restrict__ out_idx, float* __restrict__ partial) {
    __shared__ float xs[BM][BK + 1];
    __shared__ float es[BK][BN];
    __shared__ float rv[BM][17];
    __shared__ int   ri[BM][17];
    __shared__ float bestv[BM];
    __shared__ int   besti[BM];
    __shared__ float red[256];
    const int tid = threadIdx.x;
    const int tc  = tid & 15;
    const int tr  = tid >> 4;
    const int row0 = blockIdx.x * BM;
    if (tid < BM) { bestv[tid] = INFINITY; besti[tid] = 0; }
    __syncthreads();
    for (int ct = 0; ct < NE / BN; ++ct) {
        float acc[2][4] = {{0.f,0.f,0.f,0.f},{0.f,0.f,0.f,0.f}};
        for (int k0 = 0; k0 < DIM; k0 += BK) {
            {
                int r = tid >> 3;
                int k = (tid & 7) * 2;
                const float* src = &x[(size_t)(row0 + r) * DIM + k0 + k];
                xs[r][k] = src[0]; xs[r][k + 1] = src[1];
            }
            {
                int r = tid >> 4;
                int c = (tid & 15) * 4;
                float4 v = *(const float4*)&embed[(size_t)(k0 + r) * NE + ct * BN + c];
                *(float4*)&es[r][c] = v;
            }
            __syncthreads();
            #pragma unroll
            for (int kk = 0; kk < BK; ++kk) {
                float a0 = xs[tr * 2 + 0][kk];
                float a1 = xs[tr * 2 + 1][kk];
                float4 b = *(const float4*)&es[kk][tc * 4];
                acc[0][0] += a0 * b.x; acc[0][1] += a0 * b.y;
                acc[0][2] += a0 * b.z; acc[0][3] += a0 * b.w;
                acc[1][0] += a1 * b.x; acc[1][1] += a1 * b.y;
                acc[1][2] += a1 * b.z; acc[1][3] += a1 * b.w;
            }
            __syncthreads();
        }
        #pragma unroll
        for (int i = 0; i < 2; ++i) {
            float bv = INFINITY; int bj = 0;
            #pragma unroll
            for (int j = 0; j < 4; ++j) {
                int e = ct * BN + tc * 4 + j;
                float s = norms[e] - 2.0f * acc[i][j];
                if (s < bv) { bv = s; bj = e; }
            }
            rv[tr * 2 + i][tc] = bv; ri[tr * 2 + i][tc] = bj;
        }
        __syncthreads();
        if (tid < BM) {
            float bv = bestv[tid]; int bi = besti[tid];
            #pragma unroll
            for (int t = 0; t < 16; ++t) {
                float v = rv[tid][t];
                if (v < bv) { bv = v; bi = ri[tid][t]; }
            }
            bestv[tid] = bv; besti[tid] = bi;
        }
        __syncthreads();
    }
    if (tid < BM) out_idx[row0 + tid] = (float)besti[tid];
    __syncthreads();
    float local = 0.f;
    for (int i = tid; i < BM * DIM; i += 256) {
        int r = i >> 9;
        int d = i & (DIM - 1);
        int e = besti[r];
        float q  = embed[(size_t)d * NE + e];
        float xv = x[(size_t)(row0 + r) * DIM + d];
        out_q[(size_t)(row0 + r) * DIM + d] = q;
        float t = q - xv;
        local += t * t;
    }
    red[tid] = local;
    __syncthreads();
    for (int s = 128; s > 0; s >>= 1) {
        if (tid < s) red[tid] += red[tid + s];
        __syncthreads();
    }
    if (tid == 0) partial[blockIdx.x] = red[0];
}

extern "C" void kernel_launch(void* const* d_in, const int* in_sizes, int n_in,
                              void* d_out, int out_size, void* d_ws, size_t ws_size,
                              hipStream_t stream) {
    (void)in_sizes; (void)n_in; (void)out_size;
    const float* x     = (const float*)d_in[0];
    const float* embed = (const float*)d_in[1];

    float* out      = (float*)d_out;
    float* out_q    = out;
    float* out_diff = out + (size_t)NROWS * DIM;
    float* out_idx  = out_diff + 1;

    const size_t NEED = 4194304ull * 2 + 16384 + 8192 + 262144;  // ehf+el+norms+partial+idx

    char* wsb = (char*)d_ws;
    if (ws_size >= NEED) {
        unsigned short* ehf     = (unsigned short*)wsb;               // 4194304 B
        unsigned short* el      = (unsigned short*)(wsb + 4194304);   // 4194304 B
        float*          norms   = (float*)(wsb + 8388608);            //   16384 B
        float*          partial = (float*)(wsb + 8404992);            //    8192 B
        int*            idx     = (int*)(wsb + 8413184);              //  262144 B

        norms_kernel<<<NE / 256, 256, 0, stream>>>(embed, norms);
        prep_kernel<<<dim3(64, 8), 256, 0, stream>>>(embed, ehf, el);
        vq_main<<<512, 256, 0, stream>>>(x, ehf, el, norms, out_idx, idx);
        gather_kernel<<<2048, 256, 0, stream>>>(x, ehf, el, idx, out_q, partial);
        diff_kernel<<<1, 256, 0, stream>>>(partial, out_diff);
    } else {
        float* norms   = (float*)wsb;            // 16384 B
        float* partial = norms + NE;             //  8192 B
        norms_kernel<<<NE / 256, 256, 0, stream>>>(embed, norms);
        vq_kernel_fb<<<NROWS / BM, 256, 0, stream>>>(x, embed, norms, out_q, out_idx, partial);
        diff_kernel<<<1, 256, 0, stream>>>(partial, out_diff);
    }
}

// Round 12
// 387.720 us; speedup vs baseline: 1.2121x; 1.0125x over previous
//
#include <hip/hip_runtime.h>
#include <math.h>

#define DIM 512
#define NE 4096
#define NROWS 65536
#define MARGIN 1.0f            // truncated-gap gate: true gap > 0.75 ≈ 15 sigma of scan noise

typedef __attribute__((ext_vector_type(8))) short short8;
typedef __attribute__((ext_vector_type(4))) float f32x4;

// ---- bf16 helpers (round-to-nearest-even) ----
__device__ inline unsigned short f2bf(float f) {
    union { float f; unsigned int u; } v; v.f = f;
    unsigned int u = v.u;
    return (unsigned short)((u + 0x7fffu + ((u >> 16) & 1u)) >> 16);
}
__device__ inline float bf2f(unsigned short h) {
    union { unsigned int u; float f; } v; v.u = ((unsigned int)h) << 16;
    return v.f;
}
__device__ inline short hi_bf(float f) { return (short)f2bf(f); }

// fragment-ordered short index for hi image, 32-code panels (R9, proven):
//   panel p=e>>5, section sec=(d>>5)*2+((e>>4)&1), granule g=((d>>3)&3)*16+(e&15), elem d&7
__device__ __forceinline__ size_t ehf_idx(int e, int d) {
    return (size_t)(e >> 5) * 16384 +
           (size_t)(((((d >> 5) * 2 + ((e >> 4) & 1)) * 64) + ((d >> 3) & 3) * 16 + (e & 15)) * 8 + (d & 7));
}

// ---- async global->LDS (16B/lane; LDS dest = wave-uniform base + lane*16) ----
typedef __attribute__((address_space(1))) const void gconst_t;
typedef __attribute__((address_space(3))) void ldsv_t;
__device__ __forceinline__ void gload_lds16(const void* g, void* l) {
    __builtin_amdgcn_global_load_lds((gconst_t*)g, (ldsv_t*)l, 16, 0, 0);
}

// ---------------- codebook column norms (fp32, proven R1) ----------------
__global__ void norms_kernel(const float* __restrict__ embed, float* __restrict__ norms) {
    int e = blockIdx.x * blockDim.x + threadIdx.x;
    if (e < NE) {
        float s = 0.f;
        #pragma unroll 8
        for (int d = 0; d < DIM; ++d) {
            float v = embed[(size_t)d * NE + e];
            s += v * v;
        }
        norms[e] = s;
    }
}

// ---------------- transpose + hi/lo split (R9, proven) ----------------
__global__ void prep_kernel(const float* __restrict__ embed,
                            unsigned short* __restrict__ ehf,
                            unsigned short* __restrict__ el) {
    __shared__ float t[64][65];
    const int tid = threadIdx.x;                 // 256
    const int e0 = blockIdx.x * 64;              // 64 blocks
    const int d0 = blockIdx.y * 64;              // 8 blocks
    for (int i = tid; i < 4096; i += 256) {
        int r = i >> 6, c = i & 63;              // r: d, c: e  (coalesced in e)
        t[r][c] = embed[(size_t)(d0 + r) * NE + e0 + c];
    }
    __syncthreads();
    for (int i = tid; i < 4096; i += 256) {
        int r = i >> 6, c = i & 63;              // r: e, c: d
        float v = t[c][r];
        int e = e0 + r, d = d0 + c;
        unsigned short h = f2bf(v);
        ehf[ehf_idx(e, d)] = h;
        el[(size_t)e * 512 + d] = f2bf(v - bf2f(h));
    }
}

// ---------------- main: 1-pass bf16 MFMA scan, deferred epilogue (2-ct unroll),
//                  distance-5 B prefetch (ring-6), packed-u32 top-2 -> top-4 -> rescore ----
__global__ __launch_bounds__(256, 2) void vq_main(
        const float* __restrict__ x,
        const unsigned short* __restrict__ ehf,
        const unsigned short* __restrict__ el,
        const float* __restrict__ norms,
        float* __restrict__ out_idx,
        int* __restrict__ idx_ws) {

    __shared__ unsigned short ph[2][32 * 512];   // 2 x 32768 B, fragment order
    __shared__ int   bi4[128][4];
    __shared__ float bgap[128];

    const int tid = threadIdx.x;
    const int w   = tid >> 6;                    // wave 0..3
    const int l   = tid & 63;
    const int lr  = l & 15;
    const int lg  = l >> 4;
    const int row0 = blockIdx.x * 128;

    // ---- A fragments: 2 rowsets x 16 ks, single bf16 (R9, proven) ----
    short8 a[2][16];
    #pragma unroll
    for (int s = 0; s < 2; ++s) {
        const float* xp = x + (size_t)(row0 + w * 32 + s * 16 + lr) * DIM + lg * 8;
        #pragma unroll
        for (int ks = 0; ks < 16; ++ks) {
            float4 u  = *(const float4*)(xp + ks * 32);
            float4 v2 = *(const float4*)(xp + ks * 32 + 4);
            short8 h;
            h[0]=hi_bf(u.x);  h[1]=hi_bf(u.y);  h[2]=hi_bf(u.z);  h[3]=hi_bf(u.w);
            h[4]=hi_bf(v2.x); h[5]=hi_bf(v2.y); h[6]=hi_bf(v2.z); h[7]=hi_bf(v2.w);
            a[s][ks] = h;
        }
    }

    // packed top-2 per slot: key = (score_bits & ~0xFFF) | e  (scores provably > 0)
    unsigned p1[2][4], p2[2][4];
    #pragma unroll
    for (int s = 0; s < 2; ++s)
        #pragma unroll
        for (int r = 0; r < 4; ++r) { p1[s][r] = 0xFFFFFFFFu; p2[s][r] = 0xFFFFFFFFu; }

    f32x4 accA[2][2], accB[2][2];

    #define STAGE_PANEL(p, b)                                                      \
    {                                                                              \
        const unsigned short* gsrc = ehf + (size_t)(p) * 16384 + w * 4096 + l * 8; \
        unsigned short* ldst = &ph[b][w * 4096];                                   \
        _Pragma("unroll")                                                          \
        for (int j = 0; j < 8; ++j)                                                \
            gload_lds16(gsrc + j * 512, ldst + j * 512);                           \
    }

    // distance-5 software prefetch of B fragments (ring-6): reads for ks+5 issued
    // before the MFMAs of ks -> ~135 cyc of latency cover. All indices static.
    #define MFMA_PANEL(ACC, BUF)                                                   \
    {                                                                              \
        short8 bh[6][2];                                                           \
        _Pragma("unroll")                                                          \
        for (int pp = 0; pp < 5; ++pp) {                                           \
            bh[pp][0] = *(const short8*)&ph[BUF][(pp * 2 + 0) * 512 + l * 8];      \
            bh[pp][1] = *(const short8*)&ph[BUF][(pp * 2 + 1) * 512 + l * 8];      \
        }                                                                          \
        _Pragma("unroll")                                                          \
        for (int s = 0; s < 2; ++s)                                                \
            _Pragma("unroll")                                                      \
            for (int cb = 0; cb < 2; ++cb) ACC[s][cb] = (f32x4){0.f,0.f,0.f,0.f};  \
        _Pragma("unroll")                                                          \
        for (int ks = 0; ks < 16; ++ks) {                                          \
            if (ks < 11) {                                                         \
                bh[(ks + 5) % 6][0] = *(const short8*)&ph[BUF][((ks + 5) * 2 + 0) * 512 + l * 8]; \
                bh[(ks + 5) % 6][1] = *(const short8*)&ph[BUF][((ks + 5) * 2 + 1) * 512 + l * 8]; \
            }                                                                      \
            _Pragma("unroll")                                                      \
            for (int cb = 0; cb < 2; ++cb) {                                       \
                ACC[0][cb] = __builtin_amdgcn_mfma_f32_16x16x32_bf16(a[0][ks], bh[ks % 6][cb], ACC[0][cb], 0, 0, 0); \
                ACC[1][cb] = __builtin_amdgcn_mfma_f32_16x16x32_bf16(a[1][ks], bh[ks % 6][cb], ACC[1][cb], 0, 0, 0); \
            }                                                                      \
        }                                                                          \
    }

    #define EPIL_PANEL(ACC, PANEL)                                                 \
    {                                                                              \
        _Pragma("unroll")                                                          \
        for (int cb = 0; cb < 2; ++cb) {                                           \
            int e = (PANEL) * 32 + cb * 16 + lr;                                   \
            float nrm = norms[e];                                                  \
            _Pragma("unroll")                                                      \
            for (int s = 0; s < 2; ++s)                                            \
                _Pragma("unroll")                                                  \
                for (int r = 0; r < 4; ++r) {                                      \
                    float sv = fmaf(-2.0f, ACC[s][cb][r], nrm);                    \
                    unsigned pv = (__float_as_uint(sv) & 0xFFFFF000u) | (unsigned)e; \
                    unsigned t = max(p1[s][r], pv);                                \
                    p1[s][r] = min(p1[s][r], pv);                                  \
                    p2[s][r] = min(p2[s][r], t);                                   \
                }                                                                  \
        }                                                                          \
    }

    // prologue: panel 0
    STAGE_PANEL(0, 0)
    __syncthreads();
    STAGE_PANEL(1, 1)
    MFMA_PANEL(accA, 0)
    __syncthreads();

    // main: 2 panels per iteration; epilogue of the previous acc overlaps current MFMA
    #pragma unroll 1
    for (int i = 1; i < 127; i += 2) {
        // odd panel i in buf1
        STAGE_PANEL(i + 1, 0)
        MFMA_PANEL(accB, 1)
        EPIL_PANEL(accA, i - 1)
        __syncthreads();
        // even panel i+1 in buf0
        if (i + 2 < 128) STAGE_PANEL(i + 2, 1)
        MFMA_PANEL(accA, 0)
        EPIL_PANEL(accB, i)
        __syncthreads();
    }
    // tail: panel 127 in buf1
    MFMA_PANEL(accB, 1)
    EPIL_PANEL(accA, 126)
    EPIL_PANEL(accB, 127)

    #undef STAGE_PANEL
    #undef MFMA_PANEL
    #undef EPIL_PANEL

    // ---- per-slot: merge per-lane packed top-2 into global top-4 (umin/umax net) ----
    #pragma unroll
    for (int s = 0; s < 2; ++s) {
        #pragma unroll
        for (int r = 0; r < 4; ++r) {
            unsigned av[4] = { p1[s][r], p2[s][r], 0xFFFFFFFFu, 0xFFFFFFFFu };
            #pragma unroll
            for (int m = 1; m < 16; m <<= 1) {
                unsigned bv[4];
                #pragma unroll
                for (int q = 0; q < 4; ++q)
                    bv[q] = (unsigned)__shfl_xor((int)av[q], m, 64);
                unsigned cv[4];
                #pragma unroll
                for (int q = 0; q < 4; ++q) cv[q] = min(av[q], bv[3 - q]);
                #define CE(A,B) { unsigned lo = min(cv[A], cv[B]); unsigned hi = max(cv[A], cv[B]); cv[A] = lo; cv[B] = hi; }
                CE(0,2) CE(1,3) CE(0,1) CE(2,3)
                #undef CE
                #pragma unroll
                for (int q = 0; q < 4; ++q) av[q] = cv[q];
            }
            if (lr == 0) {
                int rowloc = w * 32 + s * 16 + lg * 4 + r;
                #pragma unroll
                for (int q = 0; q < 4; ++q) bi4[rowloc][q] = (int)av[q];
                float v0 = __uint_as_float(av[0] & 0xFFFFF000u);
                float v1 = __uint_as_float(av[1] & 0xFFFFF000u);
                bgap[rowloc] = v1 - v0;
            }
        }
    }
    __syncthreads();

    // ---- margin-gated exact rescore (x fp32, e = hi+lo) of the 4 candidates ----
    #pragma unroll 1
    for (int rr = 0; rr < 32; ++rr) {
        int rowloc = w * 32 + rr;
        int grow = row0 + rowloc;
        float gap = bgap[rowloc];
        int c0 = bi4[rowloc][0] & (NE - 1);
        if (gap > MARGIN) {
            if (l == 0) { out_idx[grow] = (float)c0; idx_ws[grow] = c0; }
            continue;
        }
        int cand[4];
        cand[0] = c0;
        cand[1] = bi4[rowloc][1] & (NE - 1);
        cand[2] = bi4[rowloc][2] & (NE - 1);
        cand[3] = bi4[rowloc][3] & (NE - 1);

        const float* xr = x + (size_t)grow * DIM + l * 8;
        float4 xa = *(const float4*)xr, xb = *(const float4*)(xr + 4);
        float xv[8] = {xa.x, xa.y, xa.z, xa.w, xb.x, xb.y, xb.z, xb.w};

        float d[4];
        #pragma unroll
        for (int q = 0; q < 4; ++q) {
            uint4 hv = *(const uint4*)&ehf[ehf_idx(cand[q], l * 8)];
            uint4 lv = *(const uint4*)&el[(size_t)cand[q] * 512 + l * 8];
            const unsigned short* hp = (const unsigned short*)&hv;
            const unsigned short* lp = (const unsigned short*)&lv;
            float acc = 0.f;
            #pragma unroll
            for (int j = 0; j < 8; ++j) acc += xv[j] * (bf2f(hp[j]) + bf2f(lp[j]));
            d[q] = acc;
        }
        #pragma unroll
        for (int m = 32; m >= 1; m >>= 1) {
            #pragma unroll
            for (int q = 0; q < 4; ++q) d[q] += __shfl_xor(d[q], m, 64);
        }
        if (l == 0) {
            float bs = norms[cand[0]] - 2.0f * d[0];
            int   bi = cand[0];
            #pragma unroll
            for (int q = 1; q < 4; ++q) {
                float sq = norms[cand[q]] - 2.0f * d[q];
                if (sq < bs || (sq == bs && cand[q] < bi)) { bs = sq; bi = cand[q]; }
            }
            out_idx[grow] = (float)bi;
            idx_ws[grow] = bi;
        }
    }
}

// ---------------- gather + diff partials (hi fragment-ordered + lo linear; proven) ----------------
__global__ void gather_kernel(const float* __restrict__ x,
                              const unsigned short* __restrict__ ehf,
                              const unsigned short* __restrict__ el,
                              const int* __restrict__ idx, float* __restrict__ out_q,
                              float* __restrict__ partial) {
    __shared__ float red[256];
    const int tid = threadIdx.x;
    float local = 0.f;
    #pragma unroll 1
    for (int j = 0; j < 8; ++j) {
        int o8 = blockIdx.x * 2048 + j * 256 + tid;   // octet unit
        int r  = o8 >> 6;                             // 64 octets per row
        int c8 = o8 & 63;
        int e  = idx[r];
        uint4 hv = *(const uint4*)&ehf[ehf_idx(e, c8 * 8)];
        uint4 lv = *(const uint4*)&el[(size_t)e * 512 + c8 * 8];
        const unsigned short* hp = (const unsigned short*)&hv;
        const unsigned short* lp = (const unsigned short*)&lv;
        float q[8];
        #pragma unroll
        for (int k = 0; k < 8; ++k) q[k] = bf2f(hp[k]) + bf2f(lp[k]);
        float4 xa = *(const float4*)&x[(size_t)r * DIM + c8 * 8];
        float4 xb = *(const float4*)&x[(size_t)r * DIM + c8 * 8 + 4];
        *(float4*)&out_q[(size_t)r * DIM + c8 * 8]     = make_float4(q[0], q[1], q[2], q[3]);
        *(float4*)&out_q[(size_t)r * DIM + c8 * 8 + 4] = make_float4(q[4], q[5], q[6], q[7]);
        float xs[8] = {xa.x, xa.y, xa.z, xa.w, xb.x, xb.y, xb.z, xb.w};
        #pragma unroll
        for (int k = 0; k < 8; ++k) { float t = q[k] - xs[k]; local += t * t; }
    }
    red[tid] = local;
    __syncthreads();
    for (int s = 128; s > 0; s >>= 1) {
        if (tid < s) red[tid] += red[tid + s];
        __syncthreads();
    }
    if (tid == 0) partial[blockIdx.x] = red[0];
}

// ---------------- deterministic diff reduction ----------------
__global__ void diff_kernel(const float* __restrict__ partial, float* __restrict__ out_diff) {
    __shared__ float red[256];
    float s = 0.f;
    for (int i = threadIdx.x; i < 2048; i += 256) s += partial[i];
    red[threadIdx.x] = s;
    __syncthreads();
    for (int st = 128; st > 0; st >>= 1) {
        if (threadIdx.x < st) red[threadIdx.x] += red[threadIdx.x + st];
        __syncthreads();
    }
    if (threadIdx.x == 0)
        out_diff[0] = red[0] * (1.0f / ((float)NROWS * (float)DIM));
}

// ================= fallback path (R1, proven; needs only 24 KB ws) =================
#define BM 32
#define BN 64
#define BK 16
__global__ __launch_bounds__(256) void vq_kernel_fb(
        const float* __restrict__ x, const float* __restrict__ embed,
        const float* __restrict__ norms, float* __restrict__ out_q,
        float* __restrict__ out_idx, float* __restrict__ partial) {
    __shared__ float xs[BM][BK + 1];
    __shared__ float es[BK][BN];
    __shared__ float rv[BM][17];
    __shared__ int   ri[BM][17];
    __shared__ float bestv[BM];
    __shared__ int   besti[BM];
    __shared__ float red[256];
    const int tid = threadIdx.x;
    const int tc  = tid & 15;
    const int tr  = tid >> 4;
    const int row0 = blockIdx.x * BM;
    if (tid < BM) { bestv[tid] = INFINITY; besti[tid] = 0; }
    __syncthreads();
    for (int ct = 0; ct < NE / BN; ++ct) {
        float acc[2][4] = {{0.f,0.f,0.f,0.f},{0.f,0.f,0.f,0.f}};
        for (int k0 = 0; k0 < DIM; k0 += BK) {
            {
                int r = tid >> 3;
                int k = (tid & 7) * 2;
                const float* src = &x[(size_t)(row0 + r) * DIM + k0 + k];
                xs[r][k] = src[0]; xs[r][k + 1] = src[1];
            }
            {
                int r = tid >> 4;
                int c = (tid & 15) * 4;
                float4 v = *(const float4*)&embed[(size_t)(k0 + r) * NE + ct * BN + c];
                *(float4*)&es[r][c] = v;
            }
            __syncthreads();
            #pragma unroll
            for (int kk = 0; kk < BK; ++kk) {
                float a0 = xs[tr * 2 + 0][kk];
                float a1 = xs[tr * 2 + 1][kk];
                float4 b = *(const float4*)&es[kk][tc * 4];
                acc[0][0] += a0 * b.x; acc[0][1] += a0 * b.y;
                acc[0][2] += a0 * b.z; acc[0][3] += a0 * b.w;
                acc[1][0] += a1 * b.x; acc[1][1] += a1 * b.y;
                acc[1][2] += a1 * b.z; acc[1][3] += a1 * b.w;
            }
            __syncthreads();
        }
        #pragma unroll
        for (int i = 0; i < 2; ++i) {
            float bv = INFINITY; int bj = 0;
            #pragma unroll
            for (int j = 0; j < 4; ++j) {
                int e = ct * BN + tc * 4 + j;
                float s = norms[e] - 2.0f * acc[i][j];
                if (s < bv) { bv = s; bj = e; }
            }
            rv[tr * 2 + i][tc] = bv; ri[tr * 2 + i][tc] = bj;
        }
        __syncthreads();
        if (tid < BM) {
            float bv = bestv[tid]; int bi = besti[tid];
            #pragma unroll
            for (int t = 0; t < 16; ++t) {
                float v = rv[tid][t];
                if (v < bv) { bv = v; bi = ri[tid][t]; }
            }
            bestv[tid] = bv; besti[tid] = bi;
        }
        __syncthreads();
    }
    if (tid < BM) out_idx[row0 + tid] = (float)besti[tid];
    __syncthreads();
    float local = 0.f;
    for (int i = tid; i < BM * DIM; i += 256) {
        int r = i >> 9;
        int d = i & (DIM - 1);
        int e = besti[r];
        float q  = embed[(size_t)d * NE + e];
        float xv = x[(size_t)(row0 + r) * DIM + d];
        out_q[(size_t)(row0 + r) * DIM + d] = q;
        float t = q - xv;
        local += t * t;
    }
    red[tid] = local;
    __syncthreads();
    for (int s = 128; s > 0; s >>= 1) {
        if (tid < s) red[tid] += red[tid + s];
        __syncthreads();
    }
    if (tid == 0) partial[blockIdx.x] = red[0];
}

extern "C" void kernel_launch(void* const* d_in, const int* in_sizes, int n_in,
                              void* d_out, int out_size, void* d_ws, size_t ws_size,
                              hipStream_t stream) {
    (void)in_sizes; (void)n_in; (void)out_size;
    const float* x     = (const float*)d_in[0];
    const float* embed = (const float*)d_in[1];

    float* out      = (float*)d_out;
    float* out_q    = out;
    float* out_diff = out + (size_t)NROWS * DIM;
    float* out_idx  = out_diff + 1;

    const size_t NEED = 4194304ull * 2 + 16384 + 8192 + 262144;  // ehf+el+norms+partial+idx

    char* wsb = (char*)d_ws;
    if (ws_size >= NEED) {
        unsigned short* ehf     = (unsigned short*)wsb;               // 4194304 B
        unsigned short* el      = (unsigned short*)(wsb + 4194304);   // 4194304 B
        float*          norms   = (float*)(wsb + 8388608);            //   16384 B
        float*          partial = (float*)(wsb + 8404992);            //    8192 B
        int*            idx     = (int*)(wsb + 8413184);              //  262144 B

        norms_kernel<<<NE / 256, 256, 0, stream>>>(embed, norms);
        prep_kernel<<<dim3(64, 8), 256, 0, stream>>>(embed, ehf, el);
        vq_main<<<512, 256, 0, stream>>>(x, ehf, el, norms, out_idx, idx);
        gather_kernel<<<2048, 256, 0, stream>>>(x, ehf, el, idx, out_q, partial);
        diff_kernel<<<1, 256, 0, stream>>>(partial, out_diff);
    } else {
        float* norms   = (float*)wsb;            // 16384 B
        float* partial = norms + NE;             //  8192 B
        norms_kernel<<<NE / 256, 256, 0, stream>>>(embed, norms);
        vq_kernel_fb<<<NROWS / BM, 256, 0, stream>>>(x, embed, norms, out_q, out_idx, partial);
        diff_kernel<<<1, 256, 0, stream>>>(partial, out_diff);
    }
}